// Round 6
// baseline (899.030 us; speedup 1.0000x reference)
//
#include <hip/hip_runtime.h>

#define N_NODES 100000
#define NPAD    100096   // 782 * 128 = 391 * 256; row NPAD is the all-zero dummy row
#define E_EDGES 800000

typedef _Float16 f16;
typedef _Float16 f16x4 __attribute__((ext_vector_type(4)));
typedef _Float16 f16x8 __attribute__((ext_vector_type(8)));
typedef float    f32x4 __attribute__((ext_vector_type(4)));

__device__ inline void async16(const void* g, void* l) {
    __builtin_amdgcn_global_load_lds(
        (const __attribute__((address_space(1))) void*)g,
        (__attribute__((address_space(3))) void*)l, 16, 0, 0);
}

#define BAR() __builtin_amdgcn_s_barrier()
#define WAIT_LGKM0 do { asm volatile("s_waitcnt lgkmcnt(0)" ::: "memory"); \
                        __builtin_amdgcn_sched_barrier(0); } while (0)
#define WAIT_VM8   do { asm volatile("s_waitcnt vmcnt(8)" ::: "memory"); \
                        __builtin_amdgcn_sched_barrier(0); } while (0)

// ---------------- graph build ----------------
__global__ void k_deg(const int* __restrict__ ei, int* __restrict__ deg) {
    int e = blockIdx.x * 256 + threadIdx.x;
    if (e < E_EDGES) atomicAdd(&deg[ei[e]], 1);
}

__global__ void k_scan1(const int* __restrict__ deg, int* __restrict__ off,
                        int* __restrict__ bsum, float* __restrict__ dinv) {
    __shared__ int s[256];
    int i = blockIdx.x * 256 + threadIdx.x;
    int d = (i < N_NODES) ? deg[i] : 0;
    int pd = (d + 3) & ~3;
    dinv[i] = (i < N_NODES) ? rsqrtf((float)(d + 1)) : 0.f;  // +1 self loop
    s[threadIdx.x] = pd;
    __syncthreads();
    for (int dd = 1; dd < 256; dd <<= 1) {
        int t = (threadIdx.x >= dd) ? s[threadIdx.x - dd] : 0;
        __syncthreads();
        s[threadIdx.x] += t;
        __syncthreads();
    }
    if (i < N_NODES) off[i] = s[threadIdx.x] - pd;   // exclusive
    if (threadIdx.x == 255) bsum[blockIdx.x] = s[255];
}

__global__ void k_scan2(int* __restrict__ bsum, int nb) {
    __shared__ int s[512];
    int tid = threadIdx.x;
    int v = (tid < nb) ? bsum[tid] : 0;
    s[tid] = v;
    __syncthreads();
    for (int d = 1; d < 512; d <<= 1) {
        int t = (tid >= d) ? s[tid - d] : 0;
        __syncthreads();
        s[tid] += t;
        __syncthreads();
    }
    if (tid < nb) bsum[tid] = s[tid] - v;
}

__global__ void k_scan3(int* __restrict__ off, const int* __restrict__ bsum,
                        const int* __restrict__ deg, int* __restrict__ csr) {
    int i = blockIdx.x * 256 + threadIdx.x;
    if (i >= N_NODES) return;
    int o = off[i] + bsum[blockIdx.x];
    off[i] = o;
    int d = deg[i], pd = (d + 3) & ~3;
    for (int k = d; k < pd; ++k) csr[o + k] = NPAD;   // dummy zero row
    if (i == N_NODES - 1) off[N_NODES] = o + pd;
}

__global__ void k_fill(const int* __restrict__ ei, const int* __restrict__ off,
                       int* __restrict__ cursor, int* __restrict__ csr) {
    int e = blockIdx.x * 256 + threadIdx.x;
    if (e >= E_EDGES) return;
    int dst = ei[e];
    int src = ei[E_EDGES + e];
    int pos = atomicAdd(&cursor[dst], 1);
    csr[off[dst] + pos] = src;
}

// ---------------- conversions ----------------
__global__ void k_x_to_f16(const float* __restrict__ x,
                           const float* __restrict__ dinv,
                           f16* __restrict__ xh) {
    int i = blockIdx.x * 256 + threadIdx.x;
    if (i >= N_NODES * 64) return;          // 64 float4 per node (256 ch)
    float d = dinv[i >> 6];
    float4 v = ((const float4*)x)[i];
    f16x4 o;
    o.x = (f16)(v.x * d); o.y = (f16)(v.y * d);
    o.z = (f16)(v.z * d); o.w = (f16)(v.w * d);
    ((f16x4*)xh)[i] = o;
}

__global__ void k_transpose(const float* __restrict__ W, f16* __restrict__ Wt,
                            int K, int M) {
    int m = blockIdx.x * 256 + threadIdx.x;
    int k = blockIdx.y;
    if (m < M) Wt[(size_t)m * K + k] = (f16)W[(size_t)k * M + m];
}

// ---------------- 256x256 8-phase pipelined GEMM ----------------
// C[NPAD x M] = A[NPAD x K] * Bt[M x K]^T, BK=64 split into two 32-k halves.
// 512 threads = 8 waves (2 row x 4 col), wave tile 128x64.
// LDS 128 KB: [buf][A|B][half]: A(buf,h)=buf*32768+h*8192, B = +16384 (f16).
// Per K-tile: 4 phases {dsload || stage 1 half(2 gload_lds) ; bar ; lgkm0 ;
// setprio 16 MFMA ; bar}, counted vmcnt(8) twice per tile (never 0 in loop).
// FIFO schedule (verified): prologue issues units Ak0(0),Bk0(0),Ak1(0),
// Bk1(0),Ak0(1),Bk0(1); tile t phases issue Ak1(t+1),Bk1(t+1),Ak0(t+2),
// Bk0(t+2). At every wait point exactly 4 units (8 loads) may be in flight.
// Tail: stage tile index clamped to NT-1 (targets already-dead regions with
// valid bytes) so counts stay uniform.
__device__ inline void stage2(const f16* G, int Kld, int k0, f16* lds, int tid) {
#pragma unroll
    for (int c = 0; c < 2; ++c) {
        int idx = c * 512 + tid;               // row = idx>>2, 16B seg = idx&3
        async16(G + (size_t)(idx >> 2) * Kld + k0 + (idx & 3) * 8, lds + idx * 8);
    }
}

template<int K, int M, int MODE>   // MODE: 1 = bias+relu f16, 3 = row-scale f16
__launch_bounds__(512, 2)
__global__ void k_gemm256(const f16* __restrict__ A, const f16* __restrict__ B,
                          void* __restrict__ C, const float* __restrict__ bias,
                          const float* __restrict__ dsc) {
    __shared__ __align__(16) char smem[131072];
    f16* S = (f16*)smem;
    constexpr int NT = K / 64;
    int tid = threadIdx.x;
    int wave = tid >> 6, lane = tid & 63;
    int wr = (wave >> 2) * 128, wc = (wave & 3) * 64;
    int lm = lane & 15, q = lane >> 4;

    constexpr int CB  = M / 256;
    constexpr int NWG = (NPAD / 256) * CB;
    constexpr int Qw  = NWG / 8, Rw = NWG % 8;
    int id  = blockIdx.x;
    int xcd = id & 7, pos = id >> 3;
    int nid = (xcd < Rw) ? xcd * (Qw + 1) + pos
                         : Rw * (Qw + 1) + (xcd - Rw) * Qw + pos;
    int rowBase = (nid / CB) * 256;
    int colBase = (nid % CB) * 256;

    const f16* Ag = A + (size_t)rowBase * K;
    const f16* Bg = B + (size_t)colBase * K;

    f32x4 acc[8][4] = {};

    // prologue: tile0 complete + tile1 k-half0
    stage2(Ag, K, 0,  S,                 tid);
    stage2(Bg, K, 0,  S + 16384,         tid);
    stage2(Ag, K, 32, S + 8192,          tid);
    stage2(Bg, K, 32, S + 16384 + 8192,  tid);
    stage2(Ag, K, 64, S + 32768,         tid);
    stage2(Bg, K, 64, S + 32768 + 16384, tid);
    WAIT_VM8;
    BAR();

#pragma unroll 2
    for (int t = 0; t < NT; ++t) {
        const int cb = (t & 1) * 32768;   // current buf base (f16)
        const int nb = 32768 - cb;        // next buf base
        const int t1 = (t + 1 < NT ? t + 1 : NT - 1) * 64;
        const int t2 = (t + 2 < NT ? t + 2 : NT - 1) * 64;
        f16x8 a[4], b[4];

        // ---- phase A: kslice 0, rows m0-3 (reads A.k0 + B.k0 of cur) ----
#pragma unroll
        for (int m = 0; m < 4; ++m)
            a[m] = *(const f16x8*)&S[cb + (wr + m * 16 + lm) * 32 + q * 8];
#pragma unroll
        for (int n = 0; n < 4; ++n)
            b[n] = *(const f16x8*)&S[cb + 16384 + (wc + n * 16 + lm) * 32 + q * 8];
        stage2(Ag, K, t1 + 32, S + nb + 8192, tid);           // Ak1(t+1)
        BAR(); WAIT_LGKM0;
        __builtin_amdgcn_s_setprio(1);
#pragma unroll
        for (int m = 0; m < 4; ++m)
#pragma unroll
            for (int n = 0; n < 4; ++n)
                acc[m][n] = __builtin_amdgcn_mfma_f32_16x16x32_f16(
                    a[m], b[n], acc[m][n], 0, 0, 0);
        __builtin_amdgcn_s_setprio(0);
        BAR();

        // ---- phase B: kslice 0, rows m4-7 (reuse b) ----
#pragma unroll
        for (int m = 0; m < 4; ++m)
            a[m] = *(const f16x8*)&S[cb + (wr + 64 + m * 16 + lm) * 32 + q * 8];
        stage2(Bg, K, t1 + 32, S + nb + 16384 + 8192, tid);   // Bk1(t+1)
        BAR(); WAIT_LGKM0;
        __builtin_amdgcn_s_setprio(1);
#pragma unroll
        for (int m = 0; m < 4; ++m)
#pragma unroll
            for (int n = 0; n < 4; ++n)
                acc[4 + m][n] = __builtin_amdgcn_mfma_f32_16x16x32_f16(
                    a[m], b[n], acc[4 + m][n], 0, 0, 0);
        __builtin_amdgcn_s_setprio(0);
        WAIT_VM8;   // k-half1 of cur landed (protects phase C reads)
        BAR();

        // ---- phase C: kslice 1, rows m0-3 (reads A.k1 + B.k1 of cur) ----
#pragma unroll
        for (int m = 0; m < 4; ++m)
            a[m] = *(const f16x8*)&S[cb + 8192 + (wr + m * 16 + lm) * 32 + q * 8];
#pragma unroll
        for (int n = 0; n < 4; ++n)
            b[n] = *(const f16x8*)&S[cb + 16384 + 8192 + (wc + n * 16 + lm) * 32 + q * 8];
        stage2(Ag, K, t2, S + cb, tid);                       // Ak0(t+2) -> dead region
        BAR(); WAIT_LGKM0;
        __builtin_amdgcn_s_setprio(1);
#pragma unroll
        for (int m = 0; m < 4; ++m)
#pragma unroll
            for (int n = 0; n < 4; ++n)
                acc[m][n] = __builtin_amdgcn_mfma_f32_16x16x32_f16(
                    a[m], b[n], acc[m][n], 0, 0, 0);
        __builtin_amdgcn_s_setprio(0);
        BAR();

        // ---- phase D: kslice 1, rows m4-7 ----
#pragma unroll
        for (int m = 0; m < 4; ++m)
            a[m] = *(const f16x8*)&S[cb + 8192 + (wr + 64 + m * 16 + lm) * 32 + q * 8];
        stage2(Bg, K, t2, S + cb + 16384, tid);               // Bk0(t+2) -> dead region
        BAR(); WAIT_LGKM0;
        __builtin_amdgcn_s_setprio(1);
#pragma unroll
        for (int m = 0; m < 4; ++m)
#pragma unroll
            for (int n = 0; n < 4; ++n)
                acc[4 + m][n] = __builtin_amdgcn_mfma_f32_16x16x32_f16(
                    a[m], b[n], acc[4 + m][n], 0, 0, 0);
        __builtin_amdgcn_s_setprio(0);
        WAIT_VM8;   // k-half0 of next tile landed (protects next phase A reads)
        BAR();
    }

    // ---------------- epilogue: wave-private LDS transpose -> f16x8 stores ----
    asm volatile("s_waitcnt vmcnt(0)" ::: "memory");
    __syncthreads();
    f16* Ep = S + wave * 1280;   // 2560 B per wave, row stride 80 f16
#pragma unroll
    for (int i = 0; i < 8; ++i) {
        f32x4 dr = {1.f, 1.f, 1.f, 1.f};
        if (MODE == 3)
            dr = *(const f32x4*)&dsc[rowBase + wr + i * 16 + q * 4];
#pragma unroll
        for (int n = 0; n < 4; ++n) {
            int colg = colBase + wc + n * 16 + lm;
#pragma unroll
            for (int r = 0; r < 4; ++r) {
                float v = acc[i][n][r];
                if (MODE == 1) {
                    v += bias[colg];
                    v = v > 0.f ? v : 0.f;
                }
                if (MODE == 3) v *= dr[r];
                Ep[(q * 4 + r) * 80 + n * 16 + lm] = (f16)v;
            }
        }
        int row0 = lane >> 3, c8 = lane & 7;
        f16x8 v0 = *(const f16x8*)&Ep[row0 * 80 + c8 * 8];
        f16x8 v1 = *(const f16x8*)&Ep[(row0 + 8) * 80 + c8 * 8];
        int gr0 = rowBase + wr + i * 16 + row0;
        int gc  = colBase + wc + c8 * 8;
        *(f16x8*)&((f16*)C)[(size_t)gr0 * M + gc] = v0;
        *(f16x8*)&((f16*)C)[(size_t)(gr0 + 8) * M + gc] = v1;
    }
}

// ---------------- old 128x128 GEMM (kept for the final FC, fp32 out) ----------------
template<int K, int M, int MODE>   // MODE 2 only: bias f32 out (guarded)
__launch_bounds__(256, 2)
__global__ void k_gemm(const f16* __restrict__ A, const f16* __restrict__ B,
                       void* __restrict__ C, const float* __restrict__ bias,
                       const float* __restrict__ dsc) {
    __shared__ __align__(16) char smem[16384];
    f16* As = (f16*)smem;
    f16* Bs = (f16*)(smem + 8192);
    int tid  = threadIdx.x;
    int wave = tid >> 6, lane = tid & 63;
    int wr = (wave >> 1) * 64, wc = (wave & 1) * 64;
    int lm = lane & 15, q = lane >> 4;

    constexpr int CB  = M / 128;
    constexpr int NWG = (NPAD / 128) * CB;
    constexpr int Q   = NWG / 8, R = NWG % 8;
    int id  = blockIdx.x;
    int xcd = id & 7, pos = id >> 3;
    int nid = (xcd < R) ? xcd * (Q + 1) + pos
                        : R * (Q + 1) + (xcd - R) * Q + pos;
    int rowBase = (nid / CB) * 128;
    int colBase = (nid % CB) * 128;

    f32x4 acc[4][4] = {};
    const f16* Ag = A + (size_t)rowBase * K;
    const f16* Bg = B + (size_t)colBase * K;

    int c0 = tid, c1 = tid + 256;
    for (int kt = 0; kt < K; kt += 32) {
        __syncthreads();
        async16(Ag + (size_t)(c0 >> 2) * K + kt + (c0 & 3) * 8, &As[c0 * 8]);
        async16(Ag + (size_t)(c1 >> 2) * K + kt + (c1 & 3) * 8, &As[c1 * 8]);
        async16(Bg + (size_t)(c0 >> 2) * K + kt + (c0 & 3) * 8, &Bs[c0 * 8]);
        async16(Bg + (size_t)(c1 >> 2) * K + kt + (c1 & 3) * 8, &Bs[c1 * 8]);
        __syncthreads();

        f16x8 a[4], b[4];
#pragma unroll
        for (int i = 0; i < 4; ++i) {
            a[i] = *(const f16x8*)&As[(wr + i * 16 + lm) * 32 + q * 8];
            b[i] = *(const f16x8*)&Bs[(wc + i * 16 + lm) * 32 + q * 8];
        }
#pragma unroll
        for (int i = 0; i < 4; ++i)
#pragma unroll
            for (int j = 0; j < 4; ++j)
                acc[i][j] = __builtin_amdgcn_mfma_f32_16x16x32_f16(
                    a[i], b[j], acc[i][j], 0, 0, 0);
    }

    // fp32 output (final FC) — guarded scalar stores
#pragma unroll
    for (int i = 0; i < 4; ++i) {
        int gr0 = rowBase + wr + i * 16 + q * 4;
#pragma unroll
        for (int j = 0; j < 4; ++j) {
            int gc = colBase + wc + j * 16 + lm;
            float bj = bias[gc];
#pragma unroll
            for (int r = 0; r < 4; ++r) {
                int gr = gr0 + r;
                if (gr < N_NODES)
                    ((float*)C)[(size_t)gr * M + gc] = acc[i][j][r] + bj;
            }
        }
    }
}

// ---------------- aggregation (contiguous, CH channels, prescaled rows) ----------------
template<int VE> struct VecT;
template<> struct VecT<4> { typedef f16x4 type; };
template<> struct VecT<8> { typedef f16x8 type; };

template<int CH, bool ACT>
__launch_bounds__(256)
__global__ void k_agg(const f16* __restrict__ t, const int* __restrict__ off,
                      const int* __restrict__ csr, const float* __restrict__ dinv,
                      const float* __restrict__ bias, f16* __restrict__ h) {
    constexpr int VE = CH / 64;
    typedef typename VecT<VE>::type vec;
    int node = blockIdx.x * 4 + (threadIdx.x >> 6);
    if (node >= N_NODES) return;
    int lane = threadIdx.x & 63;
    const vec* __restrict__ rows = (const vec*)t;

    vec v = rows[(size_t)node * 64 + lane];  // self (already dinv-scaled)
    float acc[VE];
#pragma unroll
    for (int j = 0; j < VE; ++j) acc[j] = (float)v[j];

    int s = off[node], e = off[node + 1];    // multiple-of-4 row, 16B aligned
    if (s < e) {
        int4 iv = *(const int4*)&csr[s];
        for (int idx = s; idx < e; idx += 4) {
            int4 nxt = *(const int4*)&csr[idx + 4];
            vec u0 = rows[(size_t)iv.x * 64 + lane];
            vec u1 = rows[(size_t)iv.y * 64 + lane];
            vec u2 = rows[(size_t)iv.z * 64 + lane];
            vec u3 = rows[(size_t)iv.w * 64 + lane];
            iv = nxt;
#pragma unroll
            for (int j = 0; j < VE; ++j)
                acc[j] += ((float)u0[j] + (float)u1[j])
                        + ((float)u2[j] + (float)u3[j]);
        }
    }

    float di = dinv[node];
    vec o;
#pragma unroll
    for (int j = 0; j < VE; ++j) {
        float r = di * acc[j];
        if (ACT) {
            r += bias[lane * VE + j];
            r = r > 0.f ? r : 0.f;
        }
        o[j] = (f16)r;
    }
    ((vec*)h)[(size_t)node * 64 + lane] = o;
}

// ---------------- launch ----------------
extern "C" void kernel_launch(void* const* d_in, const int* in_sizes, int n_in,
                              void* d_out, int out_size, void* d_ws, size_t ws_size,
                              hipStream_t stream) {
    const float* x   = (const float*)d_in[0];
    const int*   ei  = (const int*)d_in[1];
    const float* W1  = (const float*)d_in[2];
    const float* b1  = (const float*)d_in[3];
    const float* W2  = (const float*)d_in[4];
    const float* b2  = (const float*)d_in[5];
    const float* W3  = (const float*)d_in[6];
    const float* b3  = (const float*)d_in[7];
    const float* Wfc = (const float*)d_in[8];
    const float* bfc = (const float*)d_in[9];

    char* wsb = (char*)d_ws;
    size_t o = 0;
    auto alloc = [&](size_t bytes) -> void* {
        void* p = wsb + o;
        o += (bytes + 255) & ~(size_t)255;
        return p;
    };

    f16* xh   = (f16*)alloc((size_t)(NPAD + 1) * 256 * 2); // +1 dummy zero row
    f16* t    = (f16*)alloc((size_t)(NPAD + 1) * 512 * 2); // +1 dummy zero row
    f16* h    = (f16*)alloc((size_t)NPAD * 512 * 2);
    f16* Wt1  = (f16*)alloc(512 * 256 * 2);
    f16* Wt2  = (f16*)alloc(512 * 512 * 2);
    f16* Wt3  = (f16*)alloc(512 * 512 * 2);
    f16* Wtfc = (f16*)alloc(256 * 512 * 2);
    int* deg    = (int*)alloc(N_NODES * 4);
    float* dinv = (float*)alloc(NPAD * 4);
    int* off    = (int*)alloc((N_NODES + 1) * 4);
    int* cursor = (int*)alloc(N_NODES * 4);
    int* bsum   = (int*)alloc(4096 * 4);
    int* csr    = (int*)alloc(((size_t)E_EDGES + 3 * N_NODES + 8) * 4); // padded

    f16* a1 = t;   // layer-1 agg output [NPAD x 256] aliases t (free until gemm2)

    const int NB = (N_NODES + 255) / 256;   // 391; 391*256 == NPAD exactly

    hipMemsetAsync(deg, 0, N_NODES * 4, stream);
    hipMemsetAsync(cursor, 0, N_NODES * 4, stream);
    hipMemsetAsync(xh + (size_t)NPAD * 256, 0, 256 * 2, stream); // dummy row
    hipMemsetAsync(t  + (size_t)NPAD * 512, 0, 512 * 2, stream); // dummy row

    k_deg<<<(E_EDGES + 255) / 256, 256, 0, stream>>>(ei, deg);
    k_scan1<<<NB, 256, 0, stream>>>(deg, off, bsum, dinv);
    k_scan2<<<1, 512, 0, stream>>>(bsum, NB);
    k_scan3<<<NB, 256, 0, stream>>>(off, bsum, deg, csr);
    k_fill<<<(E_EDGES + 255) / 256, 256, 0, stream>>>(ei, off, cursor, csr);

    k_x_to_f16<<<(N_NODES * 64 + 255) / 256, 256, 0, stream>>>(x, dinv, xh);
    k_transpose<<<dim3(2, 256), 256, 0, stream>>>(W1, Wt1, 256, 512);
    k_transpose<<<dim3(2, 512), 256, 0, stream>>>(W2, Wt2, 512, 512);
    k_transpose<<<dim3(2, 512), 256, 0, stream>>>(W3, Wt3, 512, 512);
    k_transpose<<<dim3(1, 512), 256, 0, stream>>>(Wfc, Wtfc, 512, 256);

    constexpr int NWG256 = (NPAD / 256) * 2;   // 782 (M=512)
    constexpr int NWGFC  = (NPAD / 128) * 2;   // 1564 (old kernel, M=256)
    const int AGG_GRID = N_NODES / 4;          // 25000

    // layer 1: agg(dinv*x) @ W1 (+bias+relu in gemm epilogue)
    k_agg<256, false><<<AGG_GRID, 256, 0, stream>>>(xh, off, csr, dinv, nullptr, a1);
    k_gemm256<256, 512, 1><<<NWG256, 512, 0, stream>>>(a1, Wt1, h, b1, nullptr);
    // layers 2,3: gemm (row-scaled by dinv, contiguous out) then full-width agg
    k_gemm256<512, 512, 3><<<NWG256, 512, 0, stream>>>(h, Wt2, t, nullptr, dinv);
    k_agg<512, true><<<AGG_GRID, 256, 0, stream>>>(t, off, csr, dinv, b2, h);
    k_gemm256<512, 512, 3><<<NWG256, 512, 0, stream>>>(h, Wt3, t, nullptr, dinv);
    k_agg<512, true><<<AGG_GRID, 256, 0, stream>>>(t, off, csr, dinv, b3, h);
    // final FC (fp32 out, guarded)
    k_gemm<512, 256, 2><<<NWGFC, 256, 0, stream>>>(h, Wtfc, d_out, bfc, nullptr);
}